// Round 7
// baseline (925.962 us; speedup 1.0000x reference)
//
#include <hip/hip_runtime.h>
#include <math.h>

#define INV_TAU   20.0f
#define LOGN      6.931471805599453f   // log(1024)
#define B1        0.9f
#define B2        0.999f
#define EPS_ADAM  1e-8f

constexpr int BATCH = 8;
constexpr int N = 1024;
constexpr int M = 1024;
constexpr int NITER = 10;

// ---------- persistent (cooperative) config ----------
constexpr int P_RPB  = 32;               // rows per block
constexpr int P_NCH  = N / P_RPB;        // 32 chunks per batch
constexpr int P_NBLK = BATCH * P_NCH;    // 256 blocks = 1 per CU
constexpr int P_NTHR = 512;
constexpr int PMSZ   = P_NCH * BATCH * M;  // 262144 floats per partial buffer

__device__ inline float wave_max64(float x) {
#pragma unroll
  for (int off = 1; off < 64; off <<= 1) x = fmaxf(x, __shfl_xor(x, off));
  return x;
}
__device__ inline float wave_sum64(float x) {
#pragma unroll
  for (int off = 1; off < 64; off <<= 1) x += __shfl_xor(x, off);
  return x;
}

// zero the per-batch barrier counters (ws is poisoned 0xAA every call)
__global__ __launch_bounds__(64) void k_zero(unsigned* __restrict__ bar) {
  if (threadIdx.x < 16) bar[threadIdx.x] = 0u;
}

// One persistent kernel; cross-block sync = per-batch 32-block atomic barrier
// (XCD-local under the bid%8 mapping), 1 barrier per iteration.
__global__ __launch_bounds__(P_NTHR, 2) void k_sink(
    const float* __restrict__ la, float* __restrict__ out,
    unsigned* __restrict__ bar,
    float* __restrict__ pm0, float* __restrict__ ps0,
    float* __restrict__ pm1, float* __restrict__ ps1)
{
  __shared__ float4 cmm4[256], css4[256];   // 8 KB col-pass half-merge
  __shared__ float vloc[M];                 // 4 KB: full v for this batch
  __shared__ float u_s[P_RPB], mu_s[P_RPB], vu_s[P_RPB];

  const int blk = blockIdx.x;
  const int b   = blk & 7;         // batch -> XCD-local under bid%8 mapping
  const int c   = blk >> 3;        // row chunk 0..31
  const int i0  = c * P_RPB;
  const int tid = threadIdx.x;

  const float4* la4 = (const float4*)la;
  const float4* vloc4 = (const float4*)vloc;

  const int c4 = tid & 255;        // column float4 index (col layout)
  const int rg = tid >> 8;         // row half: 0 -> rows 0..15, 1 -> rows 16..31
  const int w    = tid >> 6;       // wave 0..7 (row layout)
  const int lane = tid & 63;

  // ---- prologue: pull my 16-row column slice into registers (scaled by 1/tau) ----
  float4 y[16];
#pragma unroll
  for (int rr = 0; rr < 16; ++rr) {
    float4 t = la4[((size_t)(b * N + i0 + (rg << 4) + rr) << 8) + c4];
    t.x *= INV_TAU; t.y *= INV_TAU; t.z *= INV_TAU; t.w *= INV_TAU;
    y[rr] = t;
  }
  vloc[tid] = 0.f; vloc[tid + 512] = 0.f;
  if (tid < P_RPB) { u_s[tid] = 0.f; mu_s[tid] = 0.f; vu_s[tid] = 0.f; }
  // replicated v-Adam state for my 2 owned entries (j0 = 2*tid, j0+1)
  float vst0 = 0.f, vm0 = 0.f, vv0 = 0.f;
  float vst1 = 0.f, vm1 = 0.f, vv1 = 0.f;
  __syncthreads();

  float p1 = 1.0f, p2 = 1.0f;

  for (int it = 0; it < NITER; ++it) {
    p1 *= B1; p2 *= B2;
    const float bc1 = 1.0f - p1, bc2 = 1.0f - p2;

    // ---- u half-step: wave-per-row; rows re-read from L2, v from LDS ----
    for (int s = 0; s < 4; ++s) {
      const int r = (w << 2) | s;                       // 0..31
      const float4* rowp = la4 + ((size_t)(b * N + i0 + r) << 8);
      float x[16];
      float mx = -INFINITY;
#pragma unroll
      for (int tq = 0; tq < 4; ++tq) {
        float4 k4 = rowp[lane + (tq << 6)];
        float4 v4 = vloc4[lane + (tq << 6)];
        x[4*tq+0] = fmaf(k4.x, INV_TAU, v4.x);
        x[4*tq+1] = fmaf(k4.y, INV_TAU, v4.y);
        x[4*tq+2] = fmaf(k4.z, INV_TAU, v4.z);
        x[4*tq+3] = fmaf(k4.w, INV_TAU, v4.w);
        mx = fmaxf(mx, fmaxf(fmaxf(x[4*tq+0], x[4*tq+1]), fmaxf(x[4*tq+2], x[4*tq+3])));
      }
      mx = wave_max64(mx);
      float ss = 0.f;
#pragma unroll
      for (int q = 0; q < 16; ++q) ss += __expf(x[q] - mx);
      ss = wave_sum64(ss);
      if (lane == 0) {
        float lse = mx + __logf(ss);
        float g   = (-LOGN - lse) - u_s[r];
        float mn  = B1 * mu_s[r] + (1.0f - B1) * g;
        float vn  = B2 * vu_s[r] + (1.0f - B2) * g * g;
        mu_s[r] = mn; vu_s[r] = vn;
        u_s[r]  = u_s[r] + (mn / bc1) / (sqrtf(vn / bc2) + EPS_ADAM);
      }
    }
    __syncthreads();   // u_s ready for col pass

    // ---- column partials from registers (two-pass, 1 exp/elem) ----
    {
      float* pmw = (it & 1) ? pm1 : pm0;
      float* psw = (it & 1) ? ps1 : ps0;
      float4 xm = make_float4(-INFINITY, -INFINITY, -INFINITY, -INFINITY);
#pragma unroll
      for (int rr = 0; rr < 16; ++rr) {
        float uu = u_s[(rg << 4) + rr];
        xm.x = fmaxf(xm.x, y[rr].x + uu); xm.y = fmaxf(xm.y, y[rr].y + uu);
        xm.z = fmaxf(xm.z, y[rr].z + uu); xm.w = fmaxf(xm.w, y[rr].w + uu);
      }
      float4 xs = make_float4(0.f, 0.f, 0.f, 0.f);
#pragma unroll
      for (int rr = 0; rr < 16; ++rr) {
        float uu = u_s[(rg << 4) + rr];
        xs.x += __expf(y[rr].x + uu - xm.x); xs.y += __expf(y[rr].y + uu - xm.y);
        xs.z += __expf(y[rr].z + uu - xm.z); xs.w += __expf(y[rr].w + uu - xm.w);
      }
      if (rg == 1) { cmm4[c4] = xm; css4[c4] = xs; }
      __syncthreads();
      if (rg == 0) {
        float4 om = cmm4[c4], os = css4[c4];
        float4 nm, ns;
        nm.x = fmaxf(xm.x, om.x); ns.x = xs.x * __expf(xm.x - nm.x) + os.x * __expf(om.x - nm.x);
        nm.y = fmaxf(xm.y, om.y); ns.y = xs.y * __expf(xm.y - nm.y) + os.y * __expf(om.y - nm.y);
        nm.z = fmaxf(xm.z, om.z); ns.z = xs.z * __expf(xm.z - nm.z) + os.z * __expf(om.z - nm.z);
        nm.w = fmaxf(xm.w, om.w); ns.w = xs.w * __expf(xm.w - nm.w) + os.w * __expf(om.w - nm.w);
        ((float4*)(pmw + c * (BATCH * M) + b * M))[c4] = nm;
        ((float4*)(psw + c * (BATCH * M) + b * M))[c4] = ns;
      }
    }

    // ---- per-batch barrier (32 blocks): release -> arrive -> spin -> acquire ----
    __threadfence();                 // make my pm/ps writes visible (release)
    __syncthreads();                 // all threads fenced before arrival
    if (tid == 0) {
      atomicAdd(bar + b, 1u);        // device-scope by default
      const unsigned target = 32u * (unsigned)(it + 1);
      while (__hip_atomic_load(bar + b, __ATOMIC_RELAXED,
                               __HIP_MEMORY_SCOPE_AGENT) < target) {
        __builtin_amdgcn_s_sleep(2);
      }
    }
    __syncthreads();
    __threadfence();                 // acquire: read fresh pm/ps

    // ---- redundant full combine + v Adam for my 2 entries (replicated) ----
    {
      const float* pmr = (it & 1) ? pm1 : pm0;
      const float* psr = (it & 1) ? ps1 : ps0;
      const int j0 = tid << 1;
      float Mx0 = -INFINITY, S0 = 0.f, Mx1 = -INFINITY, S1 = 0.f;
#pragma unroll 4
      for (int cn = 0; cn < P_NCH; ++cn) {
        const float2 m2 = *(const float2*)(pmr + cn * (BATCH * M) + b * M + j0);
        const float2 s2 = *(const float2*)(psr + cn * (BATCH * M) + b * M + j0);
        float nM = fmaxf(Mx0, m2.x);
        S0 = S0 * __expf(Mx0 - nM) + s2.x * __expf(m2.x - nM); Mx0 = nM;
        nM = fmaxf(Mx1, m2.y);
        S1 = S1 * __expf(Mx1 - nM) + s2.y * __expf(m2.y - nM); Mx1 = nM;
      }
      float lse0 = Mx0 + __logf(S0);
      float g0   = (-LOGN - lse0) - vst0;
      vm0 = B1 * vm0 + (1.0f - B1) * g0;
      vv0 = B2 * vv0 + (1.0f - B2) * g0 * g0;
      vst0 += (vm0 / bc1) / (sqrtf(vv0 / bc2) + EPS_ADAM);
      float lse1 = Mx1 + __logf(S1);
      float g1   = (-LOGN - lse1) - vst1;
      vm1 = B1 * vm1 + (1.0f - B1) * g1;
      vv1 = B2 * vv1 + (1.0f - B2) * g1 * g1;
      vst1 += (vm1 / bc1) / (sqrtf(vv1 / bc2) + EPS_ADAM);
      vloc[j0]     = vst0;
      vloc[j0 + 1] = vst1;
    }
    __syncthreads();   // vloc ready for next u-step / epilogue
  }

  // ---- plan epilogue straight from registers ----
  {
    float4 vv4 = vloc4[c4];
    float4* out4 = (float4*)out;
#pragma unroll
    for (int rr = 0; rr < 16; ++rr) {
      float uu = u_s[(rg << 4) + rr];
      float4 o;
      o.x = __expf(y[rr].x + uu + vv4.x);
      o.y = __expf(y[rr].y + uu + vv4.y);
      o.z = __expf(y[rr].z + uu + vv4.z);
      o.w = __expf(y[rr].w + uu + vv4.w);
      out4[((size_t)(b * N + i0 + (rg << 4) + rr) << 8) + c4] = o;
    }
  }
}

// ================= fallback: round-2 multi-kernel path (proven, 275 us) =================
constexpr int F_NCHUNK = 32;
constexpr int F_RPC    = N / F_NCHUNK;   // 32

__global__ __launch_bounds__(256) void k_init(float* __restrict__ ws) {
  int i = blockIdx.x * 256 + threadIdx.x;
  ws[i] = 0.0f;
}

__global__ __launch_bounds__(256) void k_row_u(
    const float* __restrict__ la, const float* __restrict__ v,
    float* __restrict__ u, float* __restrict__ mu, float* __restrict__ vu,
    float bc1, float bc2)
{
  int gw   = (blockIdx.x << 2) + (threadIdx.x >> 6);
  int lane = threadIdx.x & 63;
  int b = gw >> 10;
  const float4* rowp = (const float4*)(la + (size_t)gw * M);
  const float4* vp   = (const float4*)(v + b * M);

  float x[16];
  float m = -INFINITY;
#pragma unroll
  for (int t = 0; t < 4; ++t) {
    float4 k4 = rowp[lane + 64 * t];
    float4 v4 = vp[lane + 64 * t];
    x[4*t+0] = fmaf(k4.x, INV_TAU, v4.x);
    x[4*t+1] = fmaf(k4.y, INV_TAU, v4.y);
    x[4*t+2] = fmaf(k4.z, INV_TAU, v4.z);
    x[4*t+3] = fmaf(k4.w, INV_TAU, v4.w);
    m = fmaxf(m, fmaxf(fmaxf(x[4*t+0], x[4*t+1]), fmaxf(x[4*t+2], x[4*t+3])));
  }
  m = wave_max64(m);
  float s = 0.0f;
#pragma unroll
  for (int t = 0; t < 16; ++t) s += __expf(x[t] - m);
  s = wave_sum64(s);

  if (lane == 0) {
    float lse = m + __logf(s);
    float g   = (-LOGN - lse) - u[gw];
    float mn  = B1 * mu[gw] + (1.0f - B1) * g;
    float vn  = B2 * vu[gw] + (1.0f - B2) * g * g;
    mu[gw] = mn;
    vu[gw] = vn;
    u[gw]  = u[gw] + (mn / bc1) / (sqrtf(vn / bc2) + EPS_ADAM);
  }
}

__global__ __launch_bounds__(256) void k_col_partial(
    const float* __restrict__ la, const float* __restrict__ u,
    float* __restrict__ pm, float* __restrict__ ps)
{
  int b  = blockIdx.x >> 5;
  int cn = blockIdx.x & 31;
  int tid = threadIdx.x;
  int i0 = cn * F_RPC;

  __shared__ float su[F_RPC];
  if (tid < F_RPC) su[tid] = u[b * N + i0 + tid];
  __syncthreads();

  const float4* base = (const float4*)(la + (size_t)(b * N + i0) * M);
  float4 m = make_float4(-INFINITY, -INFINITY, -INFINITY, -INFINITY);
  float4 s = make_float4(0.f, 0.f, 0.f, 0.f);

#pragma unroll 4
  for (int i = 0; i < F_RPC; ++i) {
    float uu = su[i];
    float4 k4 = base[i * 256 + tid];
    float x, nm;
    x = fmaf(k4.x, INV_TAU, uu); nm = fmaxf(m.x, x);
    s.x = s.x * __expf(m.x - nm) + __expf(x - nm); m.x = nm;
    x = fmaf(k4.y, INV_TAU, uu); nm = fmaxf(m.y, x);
    s.y = s.y * __expf(m.y - nm) + __expf(x - nm); m.y = nm;
    x = fmaf(k4.z, INV_TAU, uu); nm = fmaxf(m.z, x);
    s.z = s.z * __expf(m.z - nm) + __expf(x - nm); m.z = nm;
    x = fmaf(k4.w, INV_TAU, uu); nm = fmaxf(m.w, x);
    s.w = s.w * __expf(m.w - nm) + __expf(x - nm); m.w = nm;
  }

  int off = cn * (BATCH * M) + b * M;
  ((float4*)(pm + off))[tid] = m;
  ((float4*)(ps + off))[tid] = s;
}

__global__ __launch_bounds__(256) void k_combine_v(
    const float* __restrict__ pm, const float* __restrict__ ps,
    float* __restrict__ v, float* __restrict__ mv, float* __restrict__ vv,
    float bc1, float bc2)
{
  int c = blockIdx.x * 256 + threadIdx.x;
  float Mx = -INFINITY, S = 0.0f;
#pragma unroll
  for (int cn = 0; cn < F_NCHUNK; ++cn) {
    float m = pm[cn * (BATCH * M) + c];
    float s = ps[cn * (BATCH * M) + c];
    float nM = fmaxf(Mx, m);
    S = S * __expf(Mx - nM) + s * __expf(m - nM);
    Mx = nM;
  }
  float lse = Mx + __logf(S);
  float g  = (-LOGN - lse) - v[c];
  float mn = B1 * mv[c] + (1.0f - B1) * g;
  float vn = B2 * vv[c] + (1.0f - B2) * g * g;
  mv[c] = mn;
  vv[c] = vn;
  v[c]  = v[c] + (mn / bc1) / (sqrtf(vn / bc2) + EPS_ADAM);
}

__global__ __launch_bounds__(256) void k_plan(
    const float* __restrict__ la, const float* __restrict__ u,
    const float* __restrict__ v, float* __restrict__ out)
{
  size_t idx = (size_t)blockIdx.x * 256 + threadIdx.x;
  int row = (int)(idx >> 8);
  int b   = row >> 10;
  int jc  = (int)(idx & 255);
  float ur  = u[row];
  float4 v4 = ((const float4*)(v + b * M))[jc];
  float4 k4 = ((const float4*)la)[idx];
  float4 o;
  o.x = __expf(fmaf(k4.x, INV_TAU, ur + v4.x));
  o.y = __expf(fmaf(k4.y, INV_TAU, ur + v4.y));
  o.z = __expf(fmaf(k4.z, INV_TAU, ur + v4.z));
  o.w = __expf(fmaf(k4.w, INV_TAU, ur + v4.w));
  ((float4*)out)[idx] = o;
}

extern "C" void kernel_launch(void* const* d_in, const int* in_sizes, int n_in,
                              void* d_out, int out_size, void* d_ws, size_t ws_size,
                              hipStream_t stream) {
  const float* la = (const float*)d_in[0];
  float* out = (float*)d_out;
  float* ws  = (float*)d_ws;

  // persistent-path ws layout
  unsigned* bar = (unsigned*)ws;           // [16] barrier counters (uses 8)
  float* pm0 = ws + 64;                    // [32][8][1024] each
  float* ps0 = pm0 + PMSZ;
  float* pm1 = ps0 + PMSZ;
  float* ps1 = pm1 + PMSZ;

  k_zero<<<1, 64, 0, stream>>>(bar);

  void* args[] = { (void*)&la, (void*)&out, (void*)&bar,
                   (void*)&pm0, (void*)&ps0, (void*)&pm1, (void*)&ps1 };
  hipError_t err = hipLaunchCooperativeKernel((const void*)k_sink,
                                              dim3(P_NBLK), dim3(P_NTHR),
                                              args, 0, stream);
  if (err != hipSuccess) {
    // fallback: proven multi-kernel path (round 2), its own ws layout
    float* u   = ws;
    float* v   = ws + 8192;
    float* mu  = ws + 16384;
    float* vu  = ws + 24576;
    float* mv  = ws + 32768;
    float* vv  = ws + 40960;
    float* pm2 = ws + 49152;
    float* ps2 = pm2 + F_NCHUNK * BATCH * M;

    k_init<<<192, 256, 0, stream>>>(ws);
    for (int it = 0; it < NITER; ++it) {
      float t = (float)(it + 1);
      float bc1 = 1.0f - powf(B1, t);
      float bc2 = 1.0f - powf(B2, t);
      k_row_u<<<(BATCH * N) / 4, 256, 0, stream>>>(la, v, u, mu, vu, bc1, bc2);
      k_col_partial<<<BATCH * F_NCHUNK, 256, 0, stream>>>(la, u, pm2, ps2);
      k_combine_v<<<(BATCH * M) / 256, 256, 0, stream>>>(pm2, ps2, v, mv, vv, bc1, bc2);
    }
    k_plan<<<(BATCH * N * M) / 4 / 256, 256, 0, stream>>>(la, u, v, out);
  }
}

// Round 9
// 255.654 us; speedup vs baseline: 3.6219x; 3.6219x over previous
//
#include <hip/hip_runtime.h>
#include <math.h>

#define INV_TAU   20.0f
#define LOGN      6.931471805599453f   // log(1024)
#define B1        0.9f
#define B2        0.999f
#define EPS_ADAM  1e-8f

constexpr int BATCH = 8;
constexpr int N = 1024;
constexpr int M = 1024;
constexpr int NITER = 10;
constexpr int CHUNKS = 64;              // 16 rows per chunk
constexpr int PMSTRIDE = BATCH * M;     // 8192 floats per chunk-plane

__device__ inline float max4f(float4 a) {
  return fmaxf(fmaxf(a.x, a.y), fmaxf(a.z, a.w));
}

// zero u,v,mu,vu,mv,vv (6 * 8192 floats) — ws is poisoned 0xAA every call
__global__ __launch_bounds__(256) void k_init(float* __restrict__ p) {
  p[blockIdx.x * 256 + threadIdx.x] = 0.f;
}

// Fused per-iteration kernel: row-LSE + u-Adam + column partials.
// Grid: 512 blocks (64 chunks x 8 batches, b = blk&7 -> XCD-local batch),
// 512 threads. Each thread holds 8 rows x float4 of the (1/tau)-scaled
// matrix in registers; the matrix is read ONCE per iteration (L2-resident).
__global__ __launch_bounds__(512, 4) void k_iter(
    const float* __restrict__ la, const float* __restrict__ vg,
    float* __restrict__ u, float* __restrict__ mu, float* __restrict__ vu,
    float* __restrict__ pm, float* __restrict__ ps,
    float bc1, float bc2)
{
  __shared__ float  wred[16][4];        // per-row per-wave partials
  __shared__ float  rowmax[16];
  __shared__ float  u_s[16];
  __shared__ float4 cmm4[256], css4[256];  // 8 KB half-merge

  const int blk = blockIdx.x;
  const int b   = blk & 7;              // batch (XCD-local under %8 round-robin)
  const int c   = blk >> 3;             // chunk 0..63
  const int i0  = c * 16;
  const int tid = threadIdx.x;
  const int c4  = tid & 255;            // float4 column
  const int rg  = tid >> 8;             // row half (rows rg*8 .. rg*8+7)
  const int wq  = (tid >> 6) & 3;       // wave within half
  const int lane = tid & 63;

  // ---- matrix slice -> registers (scaled), one coalesced pass ----
  const float4* la4 = (const float4*)la;
  float4 y[8];
#pragma unroll
  for (int rr = 0; rr < 8; ++rr) {
    float4 t = la4[((size_t)(b * N + i0 + rg * 8 + rr) << 8) + c4];
    t.x *= INV_TAU; t.y *= INV_TAU; t.z *= INV_TAU; t.w *= INV_TAU;
    y[rr] = t;
  }
  float4 v4 = ((const float4*)(vg + b * M))[c4];

  // ---- row-LSE max: 8 rows per thread, 64-wide shfl tree, LDS cross-wave ----
  float rv[8];
#pragma unroll
  for (int rr = 0; rr < 8; ++rr) {
    rv[rr] = max4f(make_float4(y[rr].x + v4.x, y[rr].y + v4.y,
                               y[rr].z + v4.z, y[rr].w + v4.w));
  }
#pragma unroll
  for (int off = 1; off < 64; off <<= 1) {
#pragma unroll
    for (int rr = 0; rr < 8; ++rr) rv[rr] = fmaxf(rv[rr], __shfl_xor(rv[rr], off));
  }
  if (lane == 0) {
#pragma unroll
    for (int rr = 0; rr < 8; ++rr) wred[rg * 8 + rr][wq] = rv[rr];
  }
  __syncthreads();
  if (tid < 16)
    rowmax[tid] = fmaxf(fmaxf(wred[tid][0], wred[tid][1]),
                        fmaxf(wred[tid][2], wred[tid][3]));
  __syncthreads();

  // ---- row-LSE sum ----
#pragma unroll
  for (int rr = 0; rr < 8; ++rr) {
    float m = rowmax[rg * 8 + rr];
    rv[rr] = __expf(y[rr].x + v4.x - m) + __expf(y[rr].y + v4.y - m) +
             __expf(y[rr].z + v4.z - m) + __expf(y[rr].w + v4.w - m);
  }
#pragma unroll
  for (int off = 1; off < 64; off <<= 1) {
#pragma unroll
    for (int rr = 0; rr < 8; ++rr) rv[rr] += __shfl_xor(rv[rr], off);
  }
  if (lane == 0) {
#pragma unroll
    for (int rr = 0; rr < 8; ++rr) wred[rg * 8 + rr][wq] = rv[rr];
  }
  __syncthreads();

  // ---- u-Adam for the block's 16 rows (state in global, L2-resident) ----
  if (tid < 16) {
    float s   = wred[tid][0] + wred[tid][1] + wred[tid][2] + wred[tid][3];
    int   gi  = b * N + i0 + tid;
    float lse = rowmax[tid] + __logf(s);
    float uo  = u[gi];
    float g   = (-LOGN - lse) - uo;
    float mn  = B1 * mu[gi] + (1.0f - B1) * g;
    float vn  = B2 * vu[gi] + (1.0f - B2) * g * g;
    mu[gi] = mn; vu[gi] = vn;
    float un = uo + (mn / bc1) / (sqrtf(vn / bc2) + EPS_ADAM);
    u[gi] = un; u_s[tid] = un;
  }
  __syncthreads();

  // ---- column partials from registers with updated u (two-pass, 1 exp/elem) ----
  float4 xm = make_float4(-INFINITY, -INFINITY, -INFINITY, -INFINITY);
#pragma unroll
  for (int rr = 0; rr < 8; ++rr) {
    float uu = u_s[rg * 8 + rr];
    xm.x = fmaxf(xm.x, y[rr].x + uu); xm.y = fmaxf(xm.y, y[rr].y + uu);
    xm.z = fmaxf(xm.z, y[rr].z + uu); xm.w = fmaxf(xm.w, y[rr].w + uu);
  }
  float4 xs = make_float4(0.f, 0.f, 0.f, 0.f);
#pragma unroll
  for (int rr = 0; rr < 8; ++rr) {
    float uu = u_s[rg * 8 + rr];
    xs.x += __expf(y[rr].x + uu - xm.x); xs.y += __expf(y[rr].y + uu - xm.y);
    xs.z += __expf(y[rr].z + uu - xm.z); xs.w += __expf(y[rr].w + uu - xm.w);
  }
  if (rg == 1) { cmm4[c4] = xm; css4[c4] = xs; }
  __syncthreads();
  if (rg == 0) {
    float4 om = cmm4[c4], os = css4[c4], nm, ns;
    nm.x = fmaxf(xm.x, om.x); ns.x = xs.x * __expf(xm.x - nm.x) + os.x * __expf(om.x - nm.x);
    nm.y = fmaxf(xm.y, om.y); ns.y = xs.y * __expf(xm.y - nm.y) + os.y * __expf(om.y - nm.y);
    nm.z = fmaxf(xm.z, om.z); ns.z = xs.z * __expf(xm.z - nm.z) + os.z * __expf(om.z - nm.z);
    nm.w = fmaxf(xm.w, om.w); ns.w = xs.w * __expf(xm.w - nm.w) + os.w * __expf(om.w - nm.w);
    ((float4*)(pm + c * PMSTRIDE + b * M))[c4] = nm;
    ((float4*)(ps + c * PMSTRIDE + b * M))[c4] = ns;
  }
}

// Combine 64 chunk-partials per column + v-Adam. Coalesced (thread = column),
// 4 independent merge chains for ILP.
__global__ __launch_bounds__(256) void k_comb(
    const float* __restrict__ pm, const float* __restrict__ ps,
    float* __restrict__ vg, float* __restrict__ mv, float* __restrict__ vv,
    float bc1, float bc2)
{
  const int cx = blockIdx.x * 256 + threadIdx.x;   // b*M + j  (0..8191)
  float m0 = -INFINITY, s0 = 0.f, m1 = -INFINITY, s1 = 0.f;
  float m2 = -INFINITY, s2 = 0.f, m3 = -INFINITY, s3 = 0.f;
#pragma unroll
  for (int cn = 0; cn < CHUNKS; cn += 4) {
    float am, nm;
    am = pm[(cn + 0) * PMSTRIDE + cx]; nm = fmaxf(m0, am);
    s0 = s0 * __expf(m0 - nm) + ps[(cn + 0) * PMSTRIDE + cx] * __expf(am - nm); m0 = nm;
    am = pm[(cn + 1) * PMSTRIDE + cx]; nm = fmaxf(m1, am);
    s1 = s1 * __expf(m1 - nm) + ps[(cn + 1) * PMSTRIDE + cx] * __expf(am - nm); m1 = nm;
    am = pm[(cn + 2) * PMSTRIDE + cx]; nm = fmaxf(m2, am);
    s2 = s2 * __expf(m2 - nm) + ps[(cn + 2) * PMSTRIDE + cx] * __expf(am - nm); m2 = nm;
    am = pm[(cn + 3) * PMSTRIDE + cx]; nm = fmaxf(m3, am);
    s3 = s3 * __expf(m3 - nm) + ps[(cn + 3) * PMSTRIDE + cx] * __expf(am - nm); m3 = nm;
  }
  float nm01 = fmaxf(m0, m1);
  float s01  = s0 * __expf(m0 - nm01) + s1 * __expf(m1 - nm01);
  float nm23 = fmaxf(m2, m3);
  float s23  = s2 * __expf(m2 - nm23) + s3 * __expf(m3 - nm23);
  float Mx   = fmaxf(nm01, nm23);
  float S    = s01 * __expf(nm01 - Mx) + s23 * __expf(nm23 - Mx);

  float lse = Mx + __logf(S);
  float vo  = vg[cx];
  float g   = (-LOGN - lse) - vo;
  float mn  = B1 * mv[cx] + (1.0f - B1) * g;
  float vn  = B2 * vv[cx] + (1.0f - B2) * g * g;
  mv[cx] = mn; vv[cx] = vn;
  vg[cx] = vo + (mn / bc1) / (sqrtf(vn / bc2) + EPS_ADAM);
}

// Final plan: out = exp(k/tau + u + v)
__global__ __launch_bounds__(256) void k_plan(
    const float* __restrict__ la, const float* __restrict__ u,
    const float* __restrict__ v, float* __restrict__ out)
{
  size_t idx = (size_t)blockIdx.x * 256 + threadIdx.x;  // float4 index
  int row = (int)(idx >> 8);
  int b   = row >> 10;
  int jc  = (int)(idx & 255);
  float ur  = u[row];
  float4 v4 = ((const float4*)(v + b * M))[jc];
  float4 k4 = ((const float4*)la)[idx];
  float4 o;
  o.x = __expf(fmaf(k4.x, INV_TAU, ur + v4.x));
  o.y = __expf(fmaf(k4.y, INV_TAU, ur + v4.y));
  o.z = __expf(fmaf(k4.z, INV_TAU, ur + v4.z));
  o.w = __expf(fmaf(k4.w, INV_TAU, ur + v4.w));
  ((float4*)out)[idx] = o;
}

extern "C" void kernel_launch(void* const* d_in, const int* in_sizes, int n_in,
                              void* d_out, int out_size, void* d_ws, size_t ws_size,
                              hipStream_t stream) {
  const float* la = (const float*)d_in[0];
  float* out = (float*)d_out;
  float* ws  = (float*)d_ws;

  float* u  = ws;                       // [8][1024]
  float* v  = ws + 8192;
  float* mu = ws + 16384;
  float* vu = ws + 24576;
  float* mv = ws + 32768;
  float* vv = ws + 40960;
  float* pm = ws + 49152;               // [64][8][1024]
  float* ps = pm + CHUNKS * PMSTRIDE;   // [64][8][1024]

  k_init<<<192, 256, 0, stream>>>(ws);  // zero u,v,mu,vu,mv,vv

  for (int it = 0; it < NITER; ++it) {
    float t = (float)(it + 1);
    float bc1 = 1.0f - powf(B1, t);
    float bc2 = 1.0f - powf(B2, t);
    k_iter<<<CHUNKS * BATCH, 512, 0, stream>>>(la, v, u, mu, vu, pm, ps, bc1, bc2);
    k_comb<<<(BATCH * M) / 256, 256, 0, stream>>>(pm, ps, v, mv, vv, bc1, bc2);
  }
  k_plan<<<(BATCH * N * M) / 4 / 256, 256, 0, stream>>>(la, u, v, out);
}

// Round 10
// 239.780 us; speedup vs baseline: 3.8617x; 1.0662x over previous
//
#include <hip/hip_runtime.h>
#include <math.h>

#define INV_TAU   20.0f
#define LOGN      6.931471805599453f   // log(1024)
#define B1        0.9f
#define B2        0.999f
#define EPS_ADAM  1e-8f

constexpr int BATCH = 8;
constexpr int N = 1024;
constexpr int M = 1024;
constexpr int NITER = 10;
constexpr int CHUNKS = 64;              // 16 rows per chunk
constexpr int PMSTRIDE = BATCH * M;     // 8192 floats per chunk-plane

__device__ inline float max4f(float4 a) {
  return fmaxf(fmaxf(a.x, a.y), fmaxf(a.z, a.w));
}

// Fused per-iteration kernel: row-LSE + u-Adam + column partials.
// 512 blocks (64 chunks x 8 batches) x 512 threads.
// __launch_bounds__(512,2): 2 waves/EU -> VGPR cap 128 (round-6-proven, no spill).
// first=1: u/mu/vu/v treated as zero (saves the init kernel and their reads).
__global__ __launch_bounds__(512, 2) void k_iter(
    const float* __restrict__ la, const float* __restrict__ vg,
    float* __restrict__ u, float* __restrict__ mu, float* __restrict__ vu,
    float* __restrict__ pm, float* __restrict__ ps,
    float bc1, float bc2, int first)
{
  __shared__ float  wred[16][4];        // per-row per-wave partials
  __shared__ float  rowmax[16];
  __shared__ float  u_s[16];
  __shared__ float4 cmm4[256], css4[256];  // 8 KB half-merge

  const int blk = blockIdx.x;
  const int b   = blk & 7;              // batch (XCD-friendly under %8 round-robin)
  const int c   = blk >> 3;             // chunk 0..63
  const int i0  = c * 16;
  const int tid = threadIdx.x;
  const int c4  = tid & 255;            // float4 column
  const int rg  = tid >> 8;             // row half (rows rg*8 .. rg*8+7)
  const int wq  = (tid >> 6) & 3;       // wave within half
  const int lane = tid & 63;

  // ---- matrix slice -> registers (scaled), one coalesced pass ----
  const float4* la4 = (const float4*)la;
  float4 y[8];
#pragma unroll
  for (int rr = 0; rr < 8; ++rr) {
    float4 t = la4[((size_t)(b * N + i0 + rg * 8 + rr) << 8) + c4];
    t.x *= INV_TAU; t.y *= INV_TAU; t.z *= INV_TAU; t.w *= INV_TAU;
    y[rr] = t;
  }
  float4 v4 = first ? make_float4(0.f, 0.f, 0.f, 0.f)
                    : ((const float4*)(vg + b * M))[c4];

  // ---- row-LSE max: 8 rows/thread, 64-lane shfl tree, LDS cross-wave ----
  float rv[8];
#pragma unroll
  for (int rr = 0; rr < 8; ++rr) {
    rv[rr] = max4f(make_float4(y[rr].x + v4.x, y[rr].y + v4.y,
                               y[rr].z + v4.z, y[rr].w + v4.w));
  }
#pragma unroll
  for (int off = 1; off < 64; off <<= 1) {
#pragma unroll
    for (int rr = 0; rr < 8; ++rr) rv[rr] = fmaxf(rv[rr], __shfl_xor(rv[rr], off));
  }
  if (lane == 0) {
#pragma unroll
    for (int rr = 0; rr < 8; ++rr) wred[rg * 8 + rr][wq] = rv[rr];
  }
  __syncthreads();
  if (tid < 16)
    rowmax[tid] = fmaxf(fmaxf(wred[tid][0], wred[tid][1]),
                        fmaxf(wred[tid][2], wred[tid][3]));
  __syncthreads();

  // ---- row-LSE sum ----
#pragma unroll
  for (int rr = 0; rr < 8; ++rr) {
    float m = rowmax[rg * 8 + rr];
    rv[rr] = __expf(y[rr].x + v4.x - m) + __expf(y[rr].y + v4.y - m) +
             __expf(y[rr].z + v4.z - m) + __expf(y[rr].w + v4.w - m);
  }
#pragma unroll
  for (int off = 1; off < 64; off <<= 1) {
#pragma unroll
    for (int rr = 0; rr < 8; ++rr) rv[rr] += __shfl_xor(rv[rr], off);
  }
  if (lane == 0) {
#pragma unroll
    for (int rr = 0; rr < 8; ++rr) wred[rg * 8 + rr][wq] = rv[rr];
  }
  __syncthreads();

  // ---- u-Adam for the block's 16 rows ----
  if (tid < 16) {
    float s   = wred[tid][0] + wred[tid][1] + wred[tid][2] + wred[tid][3];
    int   gi  = b * N + i0 + tid;
    float lse = rowmax[tid] + __logf(s);
    float uo  = first ? 0.f : u[gi];
    float g   = (-LOGN - lse) - uo;
    float mo  = first ? 0.f : mu[gi];
    float vo  = first ? 0.f : vu[gi];
    float mn  = B1 * mo + (1.0f - B1) * g;
    float vn  = B2 * vo + (1.0f - B2) * g * g;
    mu[gi] = mn; vu[gi] = vn;
    float un = uo + (mn / bc1) / (sqrtf(vn / bc2) + EPS_ADAM);
    u[gi] = un; u_s[tid] = un;
  }
  __syncthreads();

  // ---- column partials from registers with updated u (two-pass, 1 exp/elem) ----
  float4 xm = make_float4(-INFINITY, -INFINITY, -INFINITY, -INFINITY);
#pragma unroll
  for (int rr = 0; rr < 8; ++rr) {
    float uu = u_s[rg * 8 + rr];
    xm.x = fmaxf(xm.x, y[rr].x + uu); xm.y = fmaxf(xm.y, y[rr].y + uu);
    xm.z = fmaxf(xm.z, y[rr].z + uu); xm.w = fmaxf(xm.w, y[rr].w + uu);
  }
  float4 xs = make_float4(0.f, 0.f, 0.f, 0.f);
#pragma unroll
  for (int rr = 0; rr < 8; ++rr) {
    float uu = u_s[rg * 8 + rr];
    xs.x += __expf(y[rr].x + uu - xm.x); xs.y += __expf(y[rr].y + uu - xm.y);
    xs.z += __expf(y[rr].z + uu - xm.z); xs.w += __expf(y[rr].w + uu - xm.w);
  }
  if (rg == 1) { cmm4[c4] = xm; css4[c4] = xs; }
  __syncthreads();
  if (rg == 0) {
    float4 om = cmm4[c4], os = css4[c4], nm, ns;
    nm.x = fmaxf(xm.x, om.x); ns.x = xs.x * __expf(xm.x - nm.x) + os.x * __expf(om.x - nm.x);
    nm.y = fmaxf(xm.y, om.y); ns.y = xs.y * __expf(xm.y - nm.y) + os.y * __expf(om.y - nm.y);
    nm.z = fmaxf(xm.z, om.z); ns.z = xs.z * __expf(xm.z - nm.z) + os.z * __expf(om.z - nm.z);
    nm.w = fmaxf(xm.w, om.w); ns.w = xs.w * __expf(xm.w - nm.w) + os.w * __expf(om.w - nm.w);
    ((float4*)(pm + c * PMSTRIDE + b * M))[c4] = nm;
    ((float4*)(ps + c * PMSTRIDE + b * M))[c4] = ns;
  }
}

// Combine 64 chunk-partials per column + v-Adam.
// 256 blocks x 256 threads; block owns 32 columns; 8 lanes split the 64 chunks
// (8 serial merges each) -> shfl(32) -> LDS tree across 4 waves.
__global__ __launch_bounds__(256) void k_comb(
    const float* __restrict__ pm, const float* __restrict__ ps,
    float* __restrict__ vg, float* __restrict__ mv, float* __restrict__ vv,
    float bc1, float bc2, int first)
{
  __shared__ float sm[4][32], ss[4][32];

  const int tid  = threadIdx.x;
  const int w    = tid >> 6;            // wave 0..3
  const int lane = tid & 63;
  const int col5 = lane & 31;           // column within block
  const int grp  = (w << 1) | (lane >> 5);   // chunk group 0..7
  const int cx   = blockIdx.x * 32 + col5;   // global column (b*M+j), 0..8191

  float m = -INFINITY, s = 0.f;
#pragma unroll
  for (int k = 0; k < 8; ++k) {
    const int cn = (grp << 3) | k;
    float am = pm[cn * PMSTRIDE + cx];
    float as = ps[cn * PMSTRIDE + cx];
    float nm = fmaxf(m, am);
    s = s * __expf(m - nm) + as * __expf(am - nm); m = nm;
  }
  // merge the two groups within this wave
  {
    float om = __shfl_xor(m, 32);
    float os = __shfl_xor(s, 32);
    float nm = fmaxf(m, om);
    s = s * __expf(m - nm) + os * __expf(om - nm); m = nm;
  }
  if (lane < 32) { sm[w][col5] = m; ss[w][col5] = s; }
  __syncthreads();

  if (tid < 32) {
    float M0 = sm[0][tid], S0 = ss[0][tid];
#pragma unroll
    for (int ww = 1; ww < 4; ++ww) {
      float om = sm[ww][tid], os = ss[ww][tid];
      float nm = fmaxf(M0, om);
      S0 = S0 * __expf(M0 - nm) + os * __expf(om - nm); M0 = nm;
    }
    const int gc  = blockIdx.x * 32 + tid;
    float lse = M0 + __logf(S0);
    float vo  = first ? 0.f : vg[gc];
    float g   = (-LOGN - lse) - vo;
    float mo  = first ? 0.f : mv[gc];
    float vvo = first ? 0.f : vv[gc];
    float mn  = B1 * mo + (1.0f - B1) * g;
    float vn  = B2 * vvo + (1.0f - B2) * g * g;
    mv[gc] = mn; vv[gc] = vn;
    vg[gc] = vo + (mn / bc1) / (sqrtf(vn / bc2) + EPS_ADAM);
  }
}

// Final plan: out = exp(k/tau + u + v)
__global__ __launch_bounds__(256) void k_plan(
    const float* __restrict__ la, const float* __restrict__ u,
    const float* __restrict__ v, float* __restrict__ out)
{
  size_t idx = (size_t)blockIdx.x * 256 + threadIdx.x;  // float4 index
  int row = (int)(idx >> 8);
  int b   = row >> 10;
  int jc  = (int)(idx & 255);
  float ur  = u[row];
  float4 v4 = ((const float4*)(v + b * M))[jc];
  float4 k4 = ((const float4*)la)[idx];
  float4 o;
  o.x = __expf(fmaf(k4.x, INV_TAU, ur + v4.x));
  o.y = __expf(fmaf(k4.y, INV_TAU, ur + v4.y));
  o.z = __expf(fmaf(k4.z, INV_TAU, ur + v4.z));
  o.w = __expf(fmaf(k4.w, INV_TAU, ur + v4.w));
  ((float4*)out)[idx] = o;
}

extern "C" void kernel_launch(void* const* d_in, const int* in_sizes, int n_in,
                              void* d_out, int out_size, void* d_ws, size_t ws_size,
                              hipStream_t stream) {
  const float* la = (const float*)d_in[0];
  float* out = (float*)d_out;
  float* ws  = (float*)d_ws;

  float* u  = ws;                       // [8][1024]
  float* v  = ws + 8192;
  float* mu = ws + 16384;
  float* vu = ws + 24576;
  float* mv = ws + 32768;
  float* vv = ws + 40960;
  float* pm = ws + 49152;               // [64][8][1024]
  float* ps = pm + CHUNKS * PMSTRIDE;   // [64][8][1024]

  for (int it = 0; it < NITER; ++it) {
    float t = (float)(it + 1);
    float bc1 = 1.0f - powf(B1, t);
    float bc2 = 1.0f - powf(B2, t);
    int first = (it == 0) ? 1 : 0;
    k_iter<<<CHUNKS * BATCH, 512, 0, stream>>>(la, v, u, mu, vu, pm, ps,
                                               bc1, bc2, first);
    k_comb<<<(BATCH * M) / 32, 256, 0, stream>>>(pm, ps, v, mv, vv,
                                                 bc1, bc2, first);
  }
  k_plan<<<(BATCH * N * M) / 4 / 256, 256, 0, stream>>>(la, u, v, out);
}